// Round 11
// baseline (152.966 us; speedup 1.0000x reference)
//
#include <hip/hip_runtime.h>

typedef unsigned int uint;
typedef unsigned short ushort;
typedef unsigned char uchar;
typedef unsigned long long ull;
typedef __attribute__((ext_vector_type(4))) float f32x4;
typedef __attribute__((ext_vector_type(4))) uint u32x4;
typedef __attribute__((ext_vector_type(2))) uint u32x2;

#define NNODES 100000
#define NPAD   100032
#define NEDGES 1600000
#define FD 128
#define BM 64
#define RPW 10                 // rows per spmm wave; 10000 waves, 2500 blocks

__device__ __forceinline__ uint cvt_pk_bf16(float lo, float hi) {
    uint r;
    asm("v_cvt_pk_bf16_f32 %0, %1, %2" : "=v"(r) : "v"(lo), "v"(hi));
    return r;
}
__device__ __forceinline__ int swz(int row, int k) {
    return (row * 256 + k * 2) ^ ((row & 7) << 4);
}

// ---------------------------------------------------------------------------
// prep: blocks 0-15 build Wt (bf16(W^T), pre-swizzled); blocks 16+ build
// row_ptr[r] = lower_bound(edge_row, r).
// ---------------------------------------------------------------------------
__global__ __launch_bounds__(256) void prep(const float* __restrict__ W,
                                            ushort* __restrict__ Wt,
                                            const int* __restrict__ rows,
                                            int* __restrict__ ptr) {
    const int bid = blockIdx.x;
    if (bid < 16) {
        const int sid = bid * 256 + threadIdx.x;   // 4096 slots
        const int n = sid & 127, k0 = (sid >> 7) * 4;
        const float w0 = W[(k0 + 0) * FD + n];
        const float w1 = W[(k0 + 1) * FD + n];
        const float w2 = W[(k0 + 2) * FD + n];
        const float w3 = W[(k0 + 3) * FD + n];
        u32x2 p;
        p.x = cvt_pk_bf16(w0, w1);
        p.y = cvt_pk_bf16(w2, w3);
        *(u32x2*)((char*)Wt + swz(n, k0)) = p;
    } else {
        const int r = (bid - 16) * 256 + threadIdx.x;
        if (r > NNODES) return;
        int lo = 0, hi = NEDGES;
        while (lo < hi) {
            const int mid = (lo + hi) >> 1;
            const bool lt = rows[mid] < r;
            lo = lt ? mid + 1 : lo;
            hi = lt ? hi : mid;
        }
        ptr[r] = lo;
    }
}

// ---------------------------------------------------------------------------
// GEMM: S = X @ W via bf16 MFMA + per-row symmetric int8 quant (biased u8).
// ---------------------------------------------------------------------------
__global__ __launch_bounds__(256) void gemm_mfma_q8(const float* __restrict__ X,
                                                    const ushort* __restrict__ Wt,
                                                    uchar* __restrict__ S8,
                                                    float* __restrict__ scale) {
    __shared__ ushort As[BM * FD];   // 16 KB, swizzled; reused as u8 in epilogue
    __shared__ ushort Bs[FD * FD];   // 32 KB, swizzled
    const int tid = threadIdx.x;
    const int row0 = blockIdx.x * BM;

    #pragma unroll
    for (int it = 0; it < 8; ++it) {
        const int idx = tid + it * 256;
        const int r = idx >> 5, k0 = (idx & 31) * 4;
        const int grow = min(row0 + r, NNODES - 1);
        const float4 g = *(const float4*)&X[grow * FD + k0];
        u32x2 p;
        p.x = cvt_pk_bf16(g.x, g.y);
        p.y = cvt_pk_bf16(g.z, g.w);
        *(u32x2*)((char*)As + swz(r, k0)) = p;
    }
    #pragma unroll
    for (int it = 0; it < 8; ++it) {
        const int b = (tid + it * 256) * 16;
        *(u32x4*)((char*)Bs + b) = *(const u32x4*)((const char*)Wt + b);
    }
    __syncthreads();

    const int lane = tid & 63, wv = tid >> 6;
    const int l15 = lane & 15, kg = lane >> 4;
    const int arow = wv * 16 + l15;

    f32x4 acc[8];
    #pragma unroll
    for (int i = 0; i < 8; ++i) acc[i] = (f32x4)0.f;

    #pragma unroll
    for (int ks = 0; ks < 4; ++ks) {
        const int k0 = ks * 32 + kg * 8;
        const u32x4 a = *(const u32x4*)((const char*)As + swz(arow, k0));
        #pragma unroll
        for (int nf = 0; nf < 8; ++nf) {
            const u32x4 b = *(const u32x4*)((const char*)Bs + swz(nf * 16 + l15, k0));
            asm volatile("v_mfma_f32_16x16x32_bf16 %0, %1, %2, %0"
                         : "+v"(acc[nf]) : "v"(a), "v"(b));
        }
    }
    asm volatile("s_nop 7\ns_nop 7\ns_nop 7");

    __syncthreads();
    uchar* As8 = (uchar*)As;

    #pragma unroll
    for (int r = 0; r < 4; ++r) {
        float m = 0.f;
        #pragma unroll
        for (int nf = 0; nf < 8; ++nf) m = fmaxf(m, fabsf(acc[nf][r]));
        m = fmaxf(m, __shfl_xor(m, 1));
        m = fmaxf(m, __shfl_xor(m, 2));
        m = fmaxf(m, __shfl_xor(m, 4));
        m = fmaxf(m, __shfl_xor(m, 8));
        m = fmaxf(m, 1e-20f);
        const int lrow = wv * 16 + kg * 4 + r;
        if (l15 == 0) scale[row0 + lrow] = m * (1.f / 127.f);
        const float inv = 127.f / m;
        #pragma unroll
        for (int nf = 0; nf < 8; ++nf) {
            const int q = (int)rintf(acc[nf][r] * inv) + 128;   // [1,255]
            As8[lrow * FD + nf * 16 + l15] = (uchar)q;
        }
    }
    __syncthreads();
    #pragma unroll
    for (int it = 0; it < 2; ++it) {
        const int o = (tid + it * 256) * 16;
        *(u32x4*)(S8 + (size_t)row0 * FD + o) = *(const u32x4*)(As8 + o);
    }
}

// ---------------------------------------------------------------------------
// VS[e] = edge_val[e] * scale[edge_col[e]]
// ---------------------------------------------------------------------------
__global__ __launch_bounds__(256) void build_vs(const int* __restrict__ ecol,
                                                const float* __restrict__ eval_,
                                                const float* __restrict__ scale,
                                                float* __restrict__ VS) {
    const int i = blockIdx.x * 256 + threadIdx.x;
    if (i < NEDGES) VS[i] = eval_[i] * scale[ecol[i]];
}

// ---------------------------------------------------------------------------
// SpMM, r6 structure at pipeline DEPTH 2. Wave owns RPW=10 rows = one
// contiguous edge range. Per 8-edge batch: ONE combined meta load (lanes
// 0-7 cols, 8-15 VS, 16-23 rows). Rotation: 3 gather buffers (g0..g2),
// 4 meta buffers (m0..m3), 3 val/row SGPR sets. At step b:
//   GATHER  batch b+2   (from meta loaded at step b-2: 2 steps of slack)
//   LOADMETA batch b+4  (into the meta buffer consumed at step b-2)
//   PROC    batch b     (gathers issued at step b-2: 2 steps of slack)
// 12-step unrolled loop = lcm(3,4). Everything else identical to r6.
// ---------------------------------------------------------------------------
__global__ __launch_bounds__(256, 8) void spmm_d2(const int* __restrict__ rptr,
                                                  const int* __restrict__ erow,
                                                  const int* __restrict__ ecol,
                                                  const float* __restrict__ VS,
                                                  const uchar* __restrict__ S8,
                                                  const float* __restrict__ bias,
                                                  float* __restrict__ out) {
    const int wv = (blockIdx.x * 256 + threadIdx.x) >> 6;   // 10000 waves exact
    const int lane = threadIdx.x & 63;
    const int r0 = wv * RPW;
    const float2 b2 = *(const float2*)&bias[lane * 2];
    const uint voff = (uint)lane << 1;

    const int E0 = __builtin_amdgcn_readfirstlane(rptr[r0]);
    const int E1 = __builtin_amdgcn_readfirstlane(rptr[r0 + RPW]);

    const int sl = lane & 7;
    const uint* mb = (lane < 8) ? (const uint*)ecol
                   : (lane < 16) ? (const uint*)VS
                                 : (const uint*)erow;

    float a0 = 0.f, a1 = 0.f, sv = 0.f;

    if (E0 < E1) {
        const int nb = (E1 - E0 + 7) >> 3;

#define LOADMETA(M_, b_) { \
        const int i_ = min(E0 + (b_) * 8 + sl, NEDGES - 1); \
        M_ = mb[i_]; }

#define GATHER(G_, M_) { \
        _Pragma("unroll") for (int j = 0; j < 8; ++j) { \
            const uint c_ = (uint)__builtin_amdgcn_readlane((int)(M_), j); \
            G_[j] = (uint)*(const ushort*)(S8 + ((size_t)c_ << 7) + voff); } }

#define EXTRACT(V_, R_, M_) { \
        _Pragma("unroll") for (int j = 0; j < 8; ++j) { \
            V_[j] = __int_as_float(__builtin_amdgcn_readlane((int)(M_), 8 + j)); \
            R_[j] = __builtin_amdgcn_readlane((int)(M_), 16 + j); } }

#define FLUSH() { float2 o_; \
        o_.x = fmaf(-128.f, sv, a0) + b2.x; \
        o_.y = fmaf(-128.f, sv, a1) + b2.y; \
        *(float2*)&out[(size_t)rcur * FD + voff] = o_; \
        a0 = 0.f; a1 = 0.f; sv = 0.f; }

#define ACC(gj, vj) { \
        a0 = fmaf(vj, (float)(gj & 0xffu), a0); \
        a1 = fmaf(vj, (float)(gj >> 8), a1); \
        sv += vj; }

#define PROC(G_, V_, R_) { \
        _Pragma("unroll") for (int j = 0; j < 8; ++j) { \
            if (R_[j] != rcur) { FLUSH(); rcur = R_[j]; } \
            ACC(G_[j], V_[j]) } }

#define PROC_LAST(G_, V_, R_, b_) { \
        _Pragma("unroll") for (int j = 0; j < 8; ++j) { \
            if (E0 + (b_) * 8 + j < E1) { \
                if (R_[j] != rcur) { FLUSH(); rcur = R_[j]; } \
                ACC(G_[j], V_[j]) } } }

// STEP at batch b: gather b+2, load meta b+4, process b.
#define STEP(b_, GN, MN, VN, RN, ML, GC, VC, RC) { \
        if ((b_) + 2 < nb) { GATHER(GN, MN); EXTRACT(VN, RN, MN); } \
        if ((b_) + 4 < nb) LOADMETA(ML, (b_) + 4); \
        if ((b_) == nb - 1) { PROC_LAST(GC, VC, RC, b_) } \
        else { PROC(GC, VC, RC) } }

        uint m0_, m1_ = 0, m2_ = 0, m3_ = 0;
        uint g0_[8], g1_[8], g2_[8];
        float v0_[8], v1_[8], v2_[8];
        int r0_[8], r1_[8], r2_[8];

        LOADMETA(m0_, 0);
        LOADMETA(m1_, 1);
        LOADMETA(m2_, 2);
        LOADMETA(m3_, 3);
        GATHER(g0_, m0_);
        EXTRACT(v0_, r0_, m0_);
        GATHER(g1_, m1_);
        EXTRACT(v1_, r1_, m1_);
        int rcur = r0_[0];

        int b = 0;
        while (true) {   // 12-step rotation: gather %3, meta %4
            STEP(b, g2_, m2_, v2_, r2_, m0_, g0_, v0_, r0_); if (++b >= nb) break;
            STEP(b, g0_, m3_, v0_, r0_, m1_, g1_, v1_, r1_); if (++b >= nb) break;
            STEP(b, g1_, m0_, v1_, r1_, m2_, g2_, v2_, r2_); if (++b >= nb) break;
            STEP(b, g2_, m1_, v2_, r2_, m3_, g0_, v0_, r0_); if (++b >= nb) break;
            STEP(b, g0_, m2_, v0_, r0_, m0_, g1_, v1_, r1_); if (++b >= nb) break;
            STEP(b, g1_, m3_, v1_, r1_, m1_, g2_, v2_, r2_); if (++b >= nb) break;
            STEP(b, g2_, m0_, v2_, r2_, m2_, g0_, v0_, r0_); if (++b >= nb) break;
            STEP(b, g0_, m1_, v0_, r0_, m3_, g1_, v1_, r1_); if (++b >= nb) break;
            STEP(b, g1_, m2_, v1_, r1_, m0_, g2_, v2_, r2_); if (++b >= nb) break;
            STEP(b, g2_, m3_, v2_, r2_, m1_, g0_, v0_, r0_); if (++b >= nb) break;
            STEP(b, g0_, m0_, v0_, r0_, m2_, g1_, v1_, r1_); if (++b >= nb) break;
            STEP(b, g1_, m1_, v1_, r1_, m3_, g2_, v2_, r2_); if (++b >= nb) break;
        }
        FLUSH();

#undef STEP
#undef PROC_LAST
#undef PROC
#undef ACC
#undef FLUSH
#undef EXTRACT
#undef GATHER
#undef LOADMETA
    }

    // bias-only output for empty rows (rare but must be correct)
    const int rl_ = r0 + ((lane < RPW) ? lane : RPW - 1);
    const bool em = (lane < RPW) && (rptr[rl_] == rptr[rl_ + 1]);
    ull mask = __ballot(em);
    while (mask) {
        const int i = __ffsll(mask) - 1;
        mask &= mask - 1;
        *(float2*)&out[(size_t)(r0 + i) * FD + voff] = b2;
    }
}

// ---------------------------------------------------------------------------
extern "C" void kernel_launch(void* const* d_in, const int* in_sizes, int n_in,
                              void* d_out, int out_size, void* d_ws, size_t ws_size,
                              hipStream_t stream) {
    const float* X    = (const float*)d_in[0];
    const int*   erow = (const int*)d_in[1];
    const int*   ecol = (const int*)d_in[2];
    const float* eval_= (const float*)d_in[3];
    const float* W    = (const float*)d_in[4];
    const float* bias = (const float*)d_in[5];
    float* out = (float*)d_out;

    uchar* S8    = (uchar*)d_ws;                               // 12.8 MB
    float* scale = (float*)((char*)d_ws + 13u * 1024 * 1024);  // 400 KB
    int*   rpt   = (int*)((char*)d_ws + 14u * 1024 * 1024);    // 400 KB
    float* VS    = (float*)((char*)d_ws + 15u * 1024 * 1024);  // 6.4 MB
    ushort* Wt   = (ushort*)((char*)d_ws + 22u * 1024 * 1024); // 32 KB

    prep<<<16 + (NNODES + 256) / 256, 256, 0, stream>>>(W, Wt, erow, rpt);
    gemm_mfma_q8<<<NPAD / BM, 256, 0, stream>>>(X, Wt, S8, scale);
    build_vs<<<(NEDGES + 255) / 256, 256, 0, stream>>>(ecol, eval_, scale, VS);
    spmm_d2<<<NNODES / RPW / 4, 256, 0, stream>>>(rpt, erow, ecol, VS, S8, bias, out);
}

// Round 12
// 86.803 us; speedup vs baseline: 1.7622x; 1.7622x over previous
//
#include <hip/hip_runtime.h>

typedef unsigned int uint;
typedef unsigned short ushort;
typedef unsigned char uchar;
typedef unsigned long long ull;
typedef __attribute__((ext_vector_type(4))) float f32x4;
typedef __attribute__((ext_vector_type(4))) uint u32x4;
typedef __attribute__((ext_vector_type(2))) uint u32x2;

#define NNODES 100000
#define NPAD   100032
#define NEDGES 1600000
#define FD 128
#define BM 64
#define RPW 10                 // rows per spmm wave; 10000 waves, 2500 blocks

__device__ __forceinline__ uint cvt_pk_bf16(float lo, float hi) {
    uint r;
    asm("v_cvt_pk_bf16_f32 %0, %1, %2" : "=v"(r) : "v"(lo), "v"(hi));
    return r;
}
__device__ __forceinline__ int swz(int row, int k) {
    return (row * 256 + k * 2) ^ ((row & 7) << 4);
}

// ---------------------------------------------------------------------------
// prep: blocks 0-15 build Wt (bf16(W^T), pre-swizzled); blocks 16+ build
// row_ptr[r] = lower_bound(edge_row, r).
// ---------------------------------------------------------------------------
__global__ __launch_bounds__(256) void prep(const float* __restrict__ W,
                                            ushort* __restrict__ Wt,
                                            const int* __restrict__ rows,
                                            int* __restrict__ ptr) {
    const int bid = blockIdx.x;
    if (bid < 16) {
        const int sid = bid * 256 + threadIdx.x;   // 4096 slots
        const int n = sid & 127, k0 = (sid >> 7) * 4;
        const float w0 = W[(k0 + 0) * FD + n];
        const float w1 = W[(k0 + 1) * FD + n];
        const float w2 = W[(k0 + 2) * FD + n];
        const float w3 = W[(k0 + 3) * FD + n];
        u32x2 p;
        p.x = cvt_pk_bf16(w0, w1);
        p.y = cvt_pk_bf16(w2, w3);
        *(u32x2*)((char*)Wt + swz(n, k0)) = p;
    } else {
        const int r = (bid - 16) * 256 + threadIdx.x;
        if (r > NNODES) return;
        int lo = 0, hi = NEDGES;
        while (lo < hi) {
            const int mid = (lo + hi) >> 1;
            const bool lt = rows[mid] < r;
            lo = lt ? mid + 1 : lo;
            hi = lt ? hi : mid;
        }
        ptr[r] = lo;
    }
}

// ---------------------------------------------------------------------------
// GEMM: S = X @ W via bf16 MFMA + per-row symmetric int8 quant (biased u8).
// ---------------------------------------------------------------------------
__global__ __launch_bounds__(256) void gemm_mfma_q8(const float* __restrict__ X,
                                                    const ushort* __restrict__ Wt,
                                                    uchar* __restrict__ S8,
                                                    float* __restrict__ scale) {
    __shared__ ushort As[BM * FD];   // 16 KB, swizzled; reused as u8 in epilogue
    __shared__ ushort Bs[FD * FD];   // 32 KB, swizzled
    const int tid = threadIdx.x;
    const int row0 = blockIdx.x * BM;

    #pragma unroll
    for (int it = 0; it < 8; ++it) {
        const int idx = tid + it * 256;
        const int r = idx >> 5, k0 = (idx & 31) * 4;
        const int grow = min(row0 + r, NNODES - 1);
        const float4 g = *(const float4*)&X[grow * FD + k0];
        u32x2 p;
        p.x = cvt_pk_bf16(g.x, g.y);
        p.y = cvt_pk_bf16(g.z, g.w);
        *(u32x2*)((char*)As + swz(r, k0)) = p;
    }
    #pragma unroll
    for (int it = 0; it < 8; ++it) {
        const int b = (tid + it * 256) * 16;
        *(u32x4*)((char*)Bs + b) = *(const u32x4*)((const char*)Wt + b);
    }
    __syncthreads();

    const int lane = tid & 63, wv = tid >> 6;
    const int l15 = lane & 15, kg = lane >> 4;
    const int arow = wv * 16 + l15;

    f32x4 acc[8];
    #pragma unroll
    for (int i = 0; i < 8; ++i) acc[i] = (f32x4)0.f;

    #pragma unroll
    for (int ks = 0; ks < 4; ++ks) {
        const int k0 = ks * 32 + kg * 8;
        const u32x4 a = *(const u32x4*)((const char*)As + swz(arow, k0));
        #pragma unroll
        for (int nf = 0; nf < 8; ++nf) {
            const u32x4 b = *(const u32x4*)((const char*)Bs + swz(nf * 16 + l15, k0));
            asm volatile("v_mfma_f32_16x16x32_bf16 %0, %1, %2, %0"
                         : "+v"(acc[nf]) : "v"(a), "v"(b));
        }
    }
    asm volatile("s_nop 7\ns_nop 7\ns_nop 7");

    __syncthreads();
    uchar* As8 = (uchar*)As;

    #pragma unroll
    for (int r = 0; r < 4; ++r) {
        float m = 0.f;
        #pragma unroll
        for (int nf = 0; nf < 8; ++nf) m = fmaxf(m, fabsf(acc[nf][r]));
        m = fmaxf(m, __shfl_xor(m, 1));
        m = fmaxf(m, __shfl_xor(m, 2));
        m = fmaxf(m, __shfl_xor(m, 4));
        m = fmaxf(m, __shfl_xor(m, 8));
        m = fmaxf(m, 1e-20f);
        const int lrow = wv * 16 + kg * 4 + r;
        if (l15 == 0) scale[row0 + lrow] = m * (1.f / 127.f);
        const float inv = 127.f / m;
        #pragma unroll
        for (int nf = 0; nf < 8; ++nf) {
            const int q = (int)rintf(acc[nf][r] * inv) + 128;   // [1,255]
            As8[lrow * FD + nf * 16 + l15] = (uchar)q;
        }
    }
    __syncthreads();
    #pragma unroll
    for (int it = 0; it < 2; ++it) {
        const int o = (tid + it * 256) * 16;
        *(u32x4*)(S8 + (size_t)row0 * FD + o) = *(const u32x4*)(As8 + o);
    }
}

// ---------------------------------------------------------------------------
// VS[e] = edge_val[e] * scale[edge_col[e]]
// ---------------------------------------------------------------------------
__global__ __launch_bounds__(256) void build_vs(const int* __restrict__ ecol,
                                                const float* __restrict__ eval_,
                                                const float* __restrict__ scale,
                                                float* __restrict__ VS) {
    const int i = blockIdx.x * 256 + threadIdx.x;
    if (i < NEDGES) VS[i] = eval_[i] * scale[ecol[i]];
}

// ---------------------------------------------------------------------------
// SpMM = r6 structure, gathers at pipeline depth 2, NO register-cap spill.
// Wave owns RPW=10 rows = one contiguous edge range. Per 8-edge batch: ONE
// combined meta load (lanes 0-7 cols, 8-15 VS, 16-23 rows).
// Rotation (12-step unroll = lcm(gather 3, meta 4, vset 2)); at step b:
//   GATHER   batch b+2  from meta[(b+2)%4]   -> 2 PROC intervals of slack
//   EXTRACT  batch b+1  vals/rows -> SGPR set (b+1)&1   (as r6)
//   LOADMETA batch b+4  into meta[b%4]       -> 4 intervals of slack
//   PROC     batch b    (gathers g[b%3], set b&1)
// __launch_bounds__(256,4): 128-VGPR budget so the ~50-VGPR live set stays
// in registers (r11's (256,8) cap forced scratch spill: WRITE 196 MB).
// ---------------------------------------------------------------------------
__global__ __launch_bounds__(256, 4) void spmm_d2(const int* __restrict__ rptr,
                                                  const int* __restrict__ erow,
                                                  const int* __restrict__ ecol,
                                                  const float* __restrict__ VS,
                                                  const uchar* __restrict__ S8,
                                                  const float* __restrict__ bias,
                                                  float* __restrict__ out) {
    const int wv = (blockIdx.x * 256 + threadIdx.x) >> 6;   // 10000 waves exact
    const int lane = threadIdx.x & 63;
    const int r0 = wv * RPW;
    const float2 b2 = *(const float2*)&bias[lane * 2];
    const uint voff = (uint)lane << 1;

    const int E0 = __builtin_amdgcn_readfirstlane(rptr[r0]);
    const int E1 = __builtin_amdgcn_readfirstlane(rptr[r0 + RPW]);

    const int sl = lane & 7;
    const uint* mb = (lane < 8) ? (const uint*)ecol
                   : (lane < 16) ? (const uint*)VS
                                 : (const uint*)erow;

    float a0 = 0.f, a1 = 0.f, sv = 0.f;

    if (E0 < E1) {
        const int nb = (E1 - E0 + 7) >> 3;

#define LOADMETA(M_, b_) { \
        const int i_ = min(E0 + (b_) * 8 + sl, NEDGES - 1); \
        M_ = mb[i_]; }

#define GATHER(G_, M_) { \
        _Pragma("unroll") for (int j = 0; j < 8; ++j) { \
            const uint c_ = (uint)__builtin_amdgcn_readlane((int)(M_), j); \
            G_[j] = (uint)*(const ushort*)(S8 + ((size_t)c_ << 7) + voff); } }

#define EXTRACT(V_, R_, M_) { \
        _Pragma("unroll") for (int j = 0; j < 8; ++j) { \
            V_[j] = __int_as_float(__builtin_amdgcn_readlane((int)(M_), 8 + j)); \
            R_[j] = __builtin_amdgcn_readlane((int)(M_), 16 + j); } }

#define FLUSH() { float2 o_; \
        o_.x = fmaf(-128.f, sv, a0) + b2.x; \
        o_.y = fmaf(-128.f, sv, a1) + b2.y; \
        *(float2*)&out[(size_t)rcur * FD + voff] = o_; \
        a0 = 0.f; a1 = 0.f; sv = 0.f; }

#define ACC(gj, vj) { \
        a0 = fmaf(vj, (float)(gj & 0xffu), a0); \
        a1 = fmaf(vj, (float)(gj >> 8), a1); \
        sv += vj; }

#define PROC(G_, V_, R_) { \
        _Pragma("unroll") for (int j = 0; j < 8; ++j) { \
            if (R_[j] != rcur) { FLUSH(); rcur = R_[j]; } \
            ACC(G_[j], V_[j]) } }

#define PROC_LAST(G_, V_, R_, b_) { \
        _Pragma("unroll") for (int j = 0; j < 8; ++j) { \
            if (E0 + (b_) * 8 + j < E1) { \
                if (R_[j] != rcur) { FLUSH(); rcur = R_[j]; } \
                ACC(G_[j], V_[j]) } } }

// STEP at batch b: gather b+2 (GN from MG), extract b+1 (set VX/RX from MX),
// load meta b+4 (into ML), process b (GP with set VP/RP).
#define STEP(b_, GN, MG, VX, RX, MX, ML, GP, VP, RP) { \
        if ((b_) + 2 < nb) GATHER(GN, MG); \
        if ((b_) + 1 < nb) EXTRACT(VX, RX, MX); \
        if ((b_) + 4 < nb) LOADMETA(ML, (b_) + 4); \
        if ((b_) == nb - 1) { PROC_LAST(GP, VP, RP, b_) } \
        else { PROC(GP, VP, RP) } }

        uint m0_, m1_, m2_, m3_;
        uint g0_[8], g1_[8], g2_[8];
        float v0_[8], v1_[8];
        int r0v[8], r1v[8];

        LOADMETA(m0_, 0);
        LOADMETA(m1_, 1);          // clamped beyond range; unused then
        LOADMETA(m2_, 2);
        LOADMETA(m3_, 3);
        GATHER(g0_, m0_);
        GATHER(g1_, m1_);
        EXTRACT(v0_, r0v, m0_);
        int rcur = r0v[0];

        int b = 0;
        while (true) {
            STEP(b, g2_, m2_, v1_, r1v, m1_, m0_, g0_, v0_, r0v); if (++b >= nb) break;
            STEP(b, g0_, m3_, v0_, r0v, m2_, m1_, g1_, v1_, r1v); if (++b >= nb) break;
            STEP(b, g1_, m0_, v1_, r1v, m3_, m2_, g2_, v0_, r0v); if (++b >= nb) break;
            STEP(b, g2_, m1_, v0_, r0v, m0_, m3_, g0_, v1_, r1v); if (++b >= nb) break;
            STEP(b, g0_, m2_, v1_, r1v, m1_, m0_, g1_, v0_, r0v); if (++b >= nb) break;
            STEP(b, g1_, m3_, v0_, r0v, m2_, m1_, g2_, v1_, r1v); if (++b >= nb) break;
            STEP(b, g2_, m0_, v1_, r1v, m3_, m2_, g0_, v0_, r0v); if (++b >= nb) break;
            STEP(b, g0_, m1_, v0_, r0v, m0_, m3_, g1_, v1_, r1v); if (++b >= nb) break;
            STEP(b, g1_, m2_, v1_, r1v, m1_, m0_, g2_, v0_, r0v); if (++b >= nb) break;
            STEP(b, g2_, m3_, v0_, r0v, m2_, m1_, g0_, v1_, r1v); if (++b >= nb) break;
            STEP(b, g0_, m0_, v1_, r1v, m3_, m2_, g1_, v0_, r0v); if (++b >= nb) break;
            STEP(b, g1_, m1_, v0_, r0v, m0_, m3_, g2_, v1_, r1v); if (++b >= nb) break;
        }
        FLUSH();

#undef STEP
#undef PROC_LAST
#undef PROC
#undef ACC
#undef FLUSH
#undef EXTRACT
#undef GATHER
#undef LOADMETA
    }

    // bias-only output for empty rows (rare but must be correct)
    const int rl_ = r0 + ((lane < RPW) ? lane : RPW - 1);
    const bool em = (lane < RPW) && (rptr[rl_] == rptr[rl_ + 1]);
    ull mask = __ballot(em);
    while (mask) {
        const int i = __ffsll(mask) - 1;
        mask &= mask - 1;
        *(float2*)&out[(size_t)(r0 + i) * FD + voff] = b2;
    }
}

// ---------------------------------------------------------------------------
extern "C" void kernel_launch(void* const* d_in, const int* in_sizes, int n_in,
                              void* d_out, int out_size, void* d_ws, size_t ws_size,
                              hipStream_t stream) {
    const float* X    = (const float*)d_in[0];
    const int*   erow = (const int*)d_in[1];
    const int*   ecol = (const int*)d_in[2];
    const float* eval_= (const float*)d_in[3];
    const float* W    = (const float*)d_in[4];
    const float* bias = (const float*)d_in[5];
    float* out = (float*)d_out;

    uchar* S8    = (uchar*)d_ws;                               // 12.8 MB
    float* scale = (float*)((char*)d_ws + 13u * 1024 * 1024);  // 400 KB
    int*   rpt   = (int*)((char*)d_ws + 14u * 1024 * 1024);    // 400 KB
    float* VS    = (float*)((char*)d_ws + 15u * 1024 * 1024);  // 6.4 MB
    ushort* Wt   = (ushort*)((char*)d_ws + 22u * 1024 * 1024); // 32 KB

    prep<<<16 + (NNODES + 256) / 256, 256, 0, stream>>>(W, Wt, erow, rpt);
    gemm_mfma_q8<<<NPAD / BM, 256, 0, stream>>>(X, Wt, S8, scale);
    build_vs<<<(NEDGES + 255) / 256, 256, 0, stream>>>(ecol, eval_, scale, VS);
    spmm_d2<<<NNODES / RPW / 4, 256, 0, stream>>>(rpt, erow, ecol, VS, S8, bias, out);
}

// Round 13
// 84.576 us; speedup vs baseline: 1.8086x; 1.0263x over previous
//
#include <hip/hip_runtime.h>

typedef unsigned int uint;
typedef unsigned short ushort;
typedef unsigned char uchar;
typedef unsigned long long ull;
typedef __attribute__((ext_vector_type(4))) float f32x4;
typedef __attribute__((ext_vector_type(4))) uint u32x4;
typedef __attribute__((ext_vector_type(2))) uint u32x2;

#define NNODES 100000
#define NPAD   100032
#define NEDGES 1600000
#define FD 128
#define BM 64
#define RPW 10                 // rows per spmm wave; 100000/10 = 10000 waves

__device__ __forceinline__ uint cvt_pk_bf16(float lo, float hi) {
    uint r;
    asm("v_cvt_pk_bf16_f32 %0, %1, %2" : "=v"(r) : "v"(lo), "v"(hi));
    return r;
}
__device__ __forceinline__ int swz(int row, int k) {
    return (row * 256 + k * 2) ^ ((row & 7) << 4);
}

// ---------------------------------------------------------------------------
// prep: blocks 0-15 build Wt (bf16(W^T), pre-swizzled); blocks 16+ build
// row_ptr[r] = lower_bound(edge_row, r). Merged to save a launch.
// ---------------------------------------------------------------------------
__global__ __launch_bounds__(256) void prep(const float* __restrict__ W,
                                            ushort* __restrict__ Wt,
                                            const int* __restrict__ rows,
                                            int* __restrict__ ptr) {
    const int bid = blockIdx.x;
    if (bid < 16) {
        const int sid = bid * 256 + threadIdx.x;   // 4096 slots
        const int n = sid & 127, k0 = (sid >> 7) * 4;
        const float w0 = W[(k0 + 0) * FD + n];
        const float w1 = W[(k0 + 1) * FD + n];
        const float w2 = W[(k0 + 2) * FD + n];
        const float w3 = W[(k0 + 3) * FD + n];
        u32x2 p;
        p.x = cvt_pk_bf16(w0, w1);
        p.y = cvt_pk_bf16(w2, w3);
        *(u32x2*)((char*)Wt + swz(n, k0)) = p;
    } else {
        const int r = (bid - 16) * 256 + threadIdx.x;
        if (r > NNODES) return;
        int lo = 0, hi = NEDGES;
        while (lo < hi) {
            const int mid = (lo + hi) >> 1;
            const bool lt = rows[mid] < r;
            lo = lt ? mid + 1 : lo;
            hi = lt ? hi : mid;
        }
        ptr[r] = lo;
    }
}

// ---------------------------------------------------------------------------
// GEMM: S = X @ W via bf16 MFMA + per-row symmetric int8 quant (biased u8).
// ---------------------------------------------------------------------------
__global__ __launch_bounds__(256) void gemm_mfma_q8(const float* __restrict__ X,
                                                    const ushort* __restrict__ Wt,
                                                    uchar* __restrict__ S8,
                                                    float* __restrict__ scale) {
    __shared__ ushort As[BM * FD];   // 16 KB, swizzled; reused as u8 in epilogue
    __shared__ ushort Bs[FD * FD];   // 32 KB, swizzled
    const int tid = threadIdx.x;
    const int row0 = blockIdx.x * BM;

    #pragma unroll
    for (int it = 0; it < 8; ++it) {
        const int idx = tid + it * 256;
        const int r = idx >> 5, k0 = (idx & 31) * 4;
        const int grow = min(row0 + r, NNODES - 1);
        const float4 g = *(const float4*)&X[grow * FD + k0];
        u32x2 p;
        p.x = cvt_pk_bf16(g.x, g.y);
        p.y = cvt_pk_bf16(g.z, g.w);
        *(u32x2*)((char*)As + swz(r, k0)) = p;
    }
    #pragma unroll
    for (int it = 0; it < 8; ++it) {
        const int b = (tid + it * 256) * 16;
        *(u32x4*)((char*)Bs + b) = *(const u32x4*)((const char*)Wt + b);
    }
    __syncthreads();

    const int lane = tid & 63, wv = tid >> 6;
    const int l15 = lane & 15, kg = lane >> 4;
    const int arow = wv * 16 + l15;

    f32x4 acc[8];
    #pragma unroll
    for (int i = 0; i < 8; ++i) acc[i] = (f32x4)0.f;

    #pragma unroll
    for (int ks = 0; ks < 4; ++ks) {
        const int k0 = ks * 32 + kg * 8;
        const u32x4 a = *(const u32x4*)((const char*)As + swz(arow, k0));
        #pragma unroll
        for (int nf = 0; nf < 8; ++nf) {
            const u32x4 b = *(const u32x4*)((const char*)Bs + swz(nf * 16 + l15, k0));
            asm volatile("v_mfma_f32_16x16x32_bf16 %0, %1, %2, %0"
                         : "+v"(acc[nf]) : "v"(a), "v"(b));
        }
    }
    asm volatile("s_nop 7\ns_nop 7\ns_nop 7");

    __syncthreads();
    uchar* As8 = (uchar*)As;

    #pragma unroll
    for (int r = 0; r < 4; ++r) {
        float m = 0.f;
        #pragma unroll
        for (int nf = 0; nf < 8; ++nf) m = fmaxf(m, fabsf(acc[nf][r]));
        m = fmaxf(m, __shfl_xor(m, 1));
        m = fmaxf(m, __shfl_xor(m, 2));
        m = fmaxf(m, __shfl_xor(m, 4));
        m = fmaxf(m, __shfl_xor(m, 8));
        m = fmaxf(m, 1e-20f);
        const int lrow = wv * 16 + kg * 4 + r;
        if (l15 == 0) scale[row0 + lrow] = m * (1.f / 127.f);
        const float inv = 127.f / m;
        #pragma unroll
        for (int nf = 0; nf < 8; ++nf) {
            const int q = (int)rintf(acc[nf][r] * inv) + 128;   // [1,255]
            As8[lrow * FD + nf * 16 + l15] = (uchar)q;
        }
    }
    __syncthreads();
    #pragma unroll
    for (int it = 0; it < 2; ++it) {
        const int o = (tid + it * 256) * 16;
        *(u32x4*)(S8 + (size_t)row0 * FD + o) = *(const u32x4*)(As8 + o);
    }
}

// ---------------------------------------------------------------------------
// VS[e] = edge_val[e] * scale[edge_col[e]]
// ---------------------------------------------------------------------------
__global__ __launch_bounds__(256) void build_vs(const int* __restrict__ ecol,
                                                const float* __restrict__ eval_,
                                                const float* __restrict__ scale,
                                                float* __restrict__ VS) {
    const int i = blockIdx.x * 256 + threadIdx.x;
    if (i < NEDGES) VS[i] = eval_[i] * scale[ecol[i]];
}

// ---------------------------------------------------------------------------
// SpMM — byte-exact round-6 structure (measured 49.5 us; every structural
// deviation measured worse). Wave owns RPW=10 rows = one contiguous edge
// range. Per 8-edge batch: ONE combined meta load (lanes 0-7 cols, 8-15 VS,
// 16-23 rows), readlane -> SGPR scalars. Iteration b: issue gathers(b+1)
// from meta(b+1), load meta(b+2), then PROC batch b.
// ---------------------------------------------------------------------------
__global__ __launch_bounds__(256, 8) void spmm_pipe(const int* __restrict__ rptr,
                                                    const int* __restrict__ erow,
                                                    const int* __restrict__ ecol,
                                                    const float* __restrict__ VS,
                                                    const uchar* __restrict__ S8,
                                                    const float* __restrict__ bias,
                                                    float* __restrict__ out) {
    const int wv = (blockIdx.x * 256 + threadIdx.x) >> 6;   // 10000 waves exact
    const int lane = threadIdx.x & 63;
    const int r0 = wv * RPW;
    const float2 b2 = *(const float2*)&bias[lane * 2];

    const int E0 = __builtin_amdgcn_readfirstlane(rptr[r0]);
    const int E1 = __builtin_amdgcn_readfirstlane(rptr[r0 + RPW]);

    // per-lane combined meta base: lanes 0-7 cols, 8-15 VS, 16-23 rows
    const int sl = lane & 7;
    const uint* mbase = (lane < 8) ? (const uint*)ecol
                      : (lane < 16) ? (const uint*)VS
                                    : (const uint*)erow;

    float a0 = 0.f, a1 = 0.f, sv = 0.f;

    if (E0 < E1) {
        const int nb = (E1 - E0 + 7) >> 3;

#define LOADMETA(dst, b) { \
        const int idx_ = min(E0 + (b) * 8 + sl, NEDGES - 1); \
        dst = mbase[idx_]; }

#define GATHER(G, m) { \
        _Pragma("unroll") for (int j = 0; j < 8; ++j) { \
            const int c_ = __builtin_amdgcn_readlane((int)(m), j); \
            G[j] = (uint)*(const ushort*)(S8 + (((uint)c_) << 7) + (lane << 1)); } }

#define EXTRACT(R, V, m) { \
        _Pragma("unroll") for (int j = 0; j < 8; ++j) { \
            V[j] = __int_as_float(__builtin_amdgcn_readlane((int)(m), 8 + j)); \
            R[j] = __builtin_amdgcn_readlane((int)(m), 16 + j); } }

#define FLUSH() { float2 o_; \
        o_.x = fmaf(-128.f, sv, a0) + b2.x; \
        o_.y = fmaf(-128.f, sv, a1) + b2.y; \
        *(float2*)&out[(size_t)rcur * FD + (lane << 1)] = o_; \
        a0 = 0.f; a1 = 0.f; sv = 0.f; }

#define PROC1(G, R, V, j) { \
        if (R[j] != rcur) { FLUSH(); rcur = R[j]; } \
        const float lo_ = (float)(G[j] & 0xffu); \
        const float hi_ = (float)((G[j] >> 8) & 0xffu); \
        a0 = fmaf(V[j], lo_, a0); \
        a1 = fmaf(V[j], hi_, a1); \
        sv += V[j]; }

#define PROC_FAST(G, R, V) { \
        _Pragma("unroll") for (int j = 0; j < 8; ++j) { PROC1(G, R, V, j) } }

#define PROC_LAST(G, R, V, eb) { \
        _Pragma("unroll") for (int j = 0; j < 8; ++j) { \
            if ((eb) + j < E1) { PROC1(G, R, V, j) } } }

#define BODY(MC, MN, GC, GN, RC, VC, RN, VN, b) { \
        if ((b) + 1 < nb) { GATHER(GN, MN); EXTRACT(RN, VN, MN); } \
        if ((b) + 2 < nb) { LOADMETA(MC, (b) + 2); } \
        if ((b) == nb - 1) { PROC_LAST(GC, RC, VC, E0 + (b) * 8) } \
        else { PROC_FAST(GC, RC, VC) } }

        uint mA, mB = 0;
        uint gA[8], gB[8];
        int rA[8], rB[8];
        float vA[8], vB[8];

        LOADMETA(mA, 0);
        GATHER(gA, mA);
        EXTRACT(rA, vA, mA);
        int rcur = rA[0];
        if (nb > 1) LOADMETA(mB, 1);

        int b = 0;
        while (true) {
            BODY(mA, mB, gA, gB, rA, vA, rB, vB, b);
            if (++b >= nb) break;
            BODY(mB, mA, gB, gA, rB, vB, rA, vA, b);
            if (++b >= nb) break;
        }
        FLUSH();

#undef BODY
#undef PROC_LAST
#undef PROC_FAST
#undef PROC1
#undef FLUSH
#undef EXTRACT
#undef GATHER
#undef LOADMETA
    }

    // bias-only output for empty rows (rare but must be correct)
    const int rl = r0 + ((lane < RPW) ? lane : RPW - 1);
    const bool em = (lane < RPW) && (rptr[rl] == rptr[rl + 1]);
    ull mask = __ballot(em);
    while (mask) {
        const int i = __ffsll((ull)mask) - 1;
        mask &= mask - 1;
        *(float2*)&out[(size_t)(r0 + i) * FD + lane * 2] = b2;
    }
}

// ---------------------------------------------------------------------------
extern "C" void kernel_launch(void* const* d_in, const int* in_sizes, int n_in,
                              void* d_out, int out_size, void* d_ws, size_t ws_size,
                              hipStream_t stream) {
    const float* X    = (const float*)d_in[0];
    const int*   erow = (const int*)d_in[1];
    const int*   ecol = (const int*)d_in[2];
    const float* eval_= (const float*)d_in[3];
    const float* W    = (const float*)d_in[4];
    const float* bias = (const float*)d_in[5];
    float* out = (float*)d_out;

    uchar* S8    = (uchar*)d_ws;                               // 12.8 MB
    float* scale = (float*)((char*)d_ws + 13u * 1024 * 1024);  // 400 KB
    int*   rpt   = (int*)((char*)d_ws + 14u * 1024 * 1024);    // 400 KB
    float* VS    = (float*)((char*)d_ws + 15u * 1024 * 1024);  // 6.4 MB
    ushort* Wt   = (ushort*)((char*)d_ws + 22u * 1024 * 1024); // 32 KB

    prep<<<16 + (NNODES + 256) / 256, 256, 0, stream>>>(W, Wt, erow, rpt);
    gemm_mfma_q8<<<NPAD / BM, 256, 0, stream>>>(X, Wt, S8, scale);
    build_vs<<<(NEDGES + 255) / 256, 256, 0, stream>>>(ecol, eval_, scale, VS);
    spmm_pipe<<<NNODES / RPW / 4, 256, 0, stream>>>(rpt, erow, ecol, VS, S8, bias, out);
}